// Round 8
// baseline (203.167 us; speedup 1.0000x reference)
//
#include <hip/hip_runtime.h>
#include <hip/hip_fp16.h>
#include <hip/hip_bf16.h>
#include <math.h>

#define NEG_SLOPE 0.2f
#define BN_EPS 1e-5f
#define EPB 4096          // edges per k_edge block
#define NBMAX 1024        // max bins (64 nodes/bin) -> supports n <= 65536

typedef short  bf16x8 __attribute__((ext_vector_type(8)));
typedef float  f32x4  __attribute__((ext_vector_type(4)));

__device__ __forceinline__ float leaky(float v) {
    return v > 0.0f ? v : NEG_SLOPE * v;
}

__device__ __forceinline__ short bfbits(float f) {
    __hip_bfloat16 h = __float2bfloat16(f);
    return __builtin_bit_cast(short, h);
}

__device__ __forceinline__ bf16x8 cvt8(const float* p) {
    float4 u = *(const float4*)p;
    float4 v = *(const float4*)(p + 4);
    bf16x8 a;
    a[0] = bfbits(u.x); a[1] = bfbits(u.y); a[2] = bfbits(u.z); a[3] = bfbits(u.w);
    a[4] = bfbits(v.x); a[5] = bfbits(v.y); a[6] = bfbits(v.z); a[7] = bfbits(v.w);
    return a;
}

// ======== k_edge: LDS counting sort, 1024 threads -- UNCHANGED (control) ====
// R0-R7: edge phase invariant under wave count, atomic count, write locality,
// store coalescing, per-block waves. Held constant this round; the k_node
// split finally makes its true duration visible in top-5 for attribution.
__global__ __launch_bounds__(1024) void k_edge(
    int* __restrict__ bincnt, int* __restrict__ binbuf,
    const int* __restrict__ esrc, const int* __restrict__ edst, int E)
{
    __shared__ int hist[NBMAX];     // histogram -> scatter cursor
    __shared__ int gbase[NBMAX];    // (bin<<12) + global_off - local_base
    __shared__ int sorted[EPB];
    __shared__ int wsum[16];
    const int tid = threadIdx.x;
    const int e0 = blockIdx.x * EPB;
    const int ecnt = min(EPB, E - e0);

    hist[tid] = 0;                  // tid < 1024 == NBMAX
    __syncthreads();

    for (int i = tid; i < ecnt; i += 1024)
        atomicAdd(&hist[(unsigned)edst[e0 + i] >> 6], 1);
    __syncthreads();

    // exclusive prefix: thread t owns bin t
    const int h = hist[tid];
    int sc = h;
    const int lane = tid & 63;
    const int wv = tid >> 6;
    #pragma unroll
    for (int off = 1; off < 64; off <<= 1) {
        int v = __shfl_up(sc, off, 64);
        if (lane >= off) sc += v;
    }
    if (lane == 63) wsum[wv] = sc;
    __syncthreads();
    int base = sc - h;                      // wave-exclusive
    #pragma unroll
    for (int w_ = 0; w_ < 16; ++w_) if (w_ < wv) base += wsum[w_];

    int goff = 0;
    if (h > 0) goff = atomicAdd(&bincnt[tid * 16], h);
    gbase[tid] = (tid << 12) + goff - base;
    __syncthreads();
    hist[tid] = base;                       // cursor init = local base
    __syncthreads();

    // scatter into LDS-sorted order (LDS atomics: per-CU, cheap)
    for (int i = tid; i < ecnt; i += 1024) {
        int s = esrc[e0 + i];
        int d = edst[e0 + i];
        int pos = atomicAdd(&hist[(unsigned)d >> 6], 1);
        sorted[pos] = s | (d << 16);
    }
    __syncthreads();

    // write out: runs contiguous in LDS and global -> coalesced
    for (int i = tid; i < ecnt; i += 1024) {
        int rec = sorted[i];
        unsigned bin = (unsigned)rec >> 22;
        int dest = gbase[bin] + i;
        if (dest < (int)((bin + 1) << 12))  // overflow guard (statistically never)
            binbuf[dest] = rec;
    }
}

// ======== k_gemm: one wave = 16 rows x 128 cols, w staged bf16 in LDS =======
// (unchanged from R7 -- block-cooperative one-time w conversion into
// fragment-major LDS; inner loop = ds_read_b128 + MFMA, 2-way banks free)
__global__ __launch_bounds__(256) void k_gemm(
    const float* __restrict__ x, const float* __restrict__ w,
    __half2* __restrict__ h2, const float* __restrict__ att_s,
    const float* __restrict__ att_d, float* __restrict__ a_src,
    float* __restrict__ a_dst, int n)
{
    __shared__ short wl[16384];             // 32KB bf16, fragment-major
    const int t = threadIdx.x;

    for (int f = t; f < 2048; f += 256) {
        int m_   = f & 15;
        int g_   = (f >> 4) & 7;
        int q_   = (f >> 7) & 3;
        int k0_  = f >> 9;
        bf16x8 v = cvt8(&w[(size_t)(16 * g_ + m_) * 128 + k0_ * 32 + q_ * 8]);
        *(bf16x8*)&wl[f * 8] = v;
    }
    __syncthreads();

    const int wave = t >> 6;
    const int lane = t & 63;
    const int m = lane & 15;
    const int quad = lane >> 4;
    const int r0w = blockIdx.x * 64 + wave * 16;

    f32x4 acc[8];
    #pragma unroll
    for (int g = 0; g < 8; ++g) acc[g] = (f32x4){0.f, 0.f, 0.f, 0.f};

    const int arow = min(r0w + m, n - 1);
    const float* xrow = x + (size_t)arow * 128 + quad * 8;

    #pragma unroll
    for (int k0 = 0; k0 < 4; ++k0) {
        bf16x8 a = cvt8(xrow + k0 * 32);
        #pragma unroll
        for (int g = 0; g < 8; ++g) {
            bf16x8 b = *(const bf16x8*)&wl[(((k0 * 4 + quad) * 8 + g) * 16 + m) * 8];
            acc[g] = __builtin_amdgcn_mfma_f32_16x16x32_bf16(a, b, acc[g], 0, 0, 0);
        }
    }

    float asv[8], adv[8];
    #pragma unroll
    for (int g = 0; g < 8; ++g) {
        asv[g] = att_s[16 * g + m];
        adv[g] = att_d[16 * g + m];
    }
    float ss[4][4], sd[4][4];          // [reg][head]
    #pragma unroll
    for (int reg = 0; reg < 4; ++reg) {
        #pragma unroll
        for (int h = 0; h < 4; ++h) {
            float ps = acc[2 * h][reg] * asv[2 * h] + acc[2 * h + 1][reg] * asv[2 * h + 1];
            float pd = acc[2 * h][reg] * adv[2 * h] + acc[2 * h + 1][reg] * adv[2 * h + 1];
            #pragma unroll
            for (int msk = 1; msk <= 8; msk <<= 1) {
                ps += __shfl_xor(ps, msk, 64);
                pd += __shfl_xor(pd, msk, 64);
            }
            ss[reg][h] = ps; sd[reg][h] = pd;
        }
    }
    if (m == 0) {
        #pragma unroll
        for (int reg = 0; reg < 4; ++reg) {
            int grow = r0w + quad * 4 + reg;
            if (grow < n) {
                ((float4*)a_src)[grow] = make_float4(ss[reg][0], ss[reg][1], ss[reg][2], ss[reg][3]);
                ((float4*)a_dst)[grow] = make_float4(sd[reg][0], sd[reg][1], sd[reg][2], sd[reg][3]);
            }
        }
    }

    #pragma unroll
    for (int reg = 0; reg < 4; ++reg) {
        int grow = r0w + quad * 4 + reg;
        #pragma unroll
        for (int g = 0; g < 8; ++g) {
            float v0 = acc[g][reg];
            float v1 = __shfl_xor(v0, 1, 64);
            if (!(m & 1) && grow < n)
                h2[(size_t)grow * 64 + 8 * g + (m >> 1)] = __floats2half2_rn(v0, v1);
        }
    }
}

// ======== k_node: deep-MLP version -- 8 gather chains + a_src prefetch ======
// R7 arithmetic: 2.5M random transactions x ~400cy / 52us => only ~31
// outstanding loads per CU ~= 4 per wave -- exactly the old 4-chain gather
// plus an unpipelined per-node a_src round-trip. Latency-bound, so raise
// per-wave MLP: (a) PV gather widened to 8 independent chains (32 slots/iter;
// deg<=31 covers 99.97% of nodes in ONE iteration; padded-slot waste equals
// the old 16-slot scheme since ceil(17/32) pads ~= ceil(17/16) pads),
// (b) software pipeline over nodes: node it+1's a_src/a_dst gather issues
// between node it's softmax and PV, hiding its round-trip under the PV loop.
// Split into TWO dispatches (bin0/pboff params) so each half ~26us -> top-5
// finally attributes k_edge/k_gemm/bn_apply.
// salpha stride 72 (72%32==8): gather-read bank = 8*head+g -> 16 distinct
// banks. Lanes >= degT keep myS=0 -> padded gathers re-read node 0's row
// (L1-hot), alpha exactly 0. All shfl sites run with all 64 lanes active.
__global__ __launch_bounds__(256) void k_node(
    const int* __restrict__ bincnt, const int* __restrict__ binbuf,
    const float* __restrict__ a_src, const float* __restrict__ a_dst,
    const __half2* __restrict__ h2, const float* __restrict__ bias,
    float* __restrict__ out, float* __restrict__ pbuf, int n,
    int bin0, int pboff)
{
    __shared__ unsigned short slotsrc[32 * 64];
    __shared__ int cnt2[32];
    __shared__ float salpha[4][4][72];
    __shared__ float pb[4][256];
    const int bin = bin0 + (blockIdx.x >> 1);
    const int hsub = blockIdx.x & 1;
    const int tid = threadIdx.x;

    if (tid < 32) cnt2[tid] = 0;
    __syncthreads();

    const int cnt = min(bincnt[bin * 16], 4096);
    const int* bb = binbuf + (size_t)bin * 4096;
    for (int i = tid; i < cnt; i += 256) {
        int e = bb[i];
        int d6 = (e >> 16) & 63;
        if ((d6 >> 5) == hsub) {
            int o = atomicAdd(&cnt2[d6 & 31], 1);
            if (o < 63) slotsrc[(d6 & 31) * 64 + o] = (unsigned short)e;
        }
    }
    __syncthreads();

    const int wv = tid >> 6;
    const int lane = tid & 63;
    const int g  = lane >> 4;
    const int c4 = lane & 15;
    const int head = c4 >> 2;
    const float* ap = &salpha[wv][head][0];
    const float4* h4 = (const float4*)h2;
    const float4* as4 = (const float4*)a_src;
    const float4* ad4 = (const float4*)a_dst;
    const float4 b0 = ((const float4*)bias)[2 * c4];
    const float4 b1 = ((const float4*)bias)[2 * c4 + 1];

    float s8[8], q8[8];
    #pragma unroll
    for (int j = 0; j < 8; ++j) { s8[j] = 0.f; q8[j] = 0.f; }

    // ---- prologue: prefetch node 0 of this wave ----
    int dl_n = wv * 8;
    int d_n = bin * 64 + hsub * 32 + dl_n;
    int deg_n = min(cnt2[dl_n], 63);
    int myS_n = 0;
    float4 as_n = make_float4(0.f, 0.f, 0.f, 0.f);
    if (lane < deg_n + 1) {
        myS_n = (lane < deg_n) ? (int)slotsrc[dl_n * 64 + lane] : d_n;
        as_n = as4[myS_n];                 // safe even for tail nodes (in-ws)
    }
    float4 ad_n = ad4[d_n];

    for (int it = 0; it < 8; ++it) {
        const int d_c = d_n;
        const int degT_c = deg_n + 1;
        const int myS_c = myS_n;
        const float4 as_c = as_n;
        const float4 ad_c = ad_n;

        // ---- softmax for current node ----
        float4 ex = make_float4(0.f, 0.f, 0.f, 0.f);
        if (lane < degT_c) {
            ex = make_float4(__expf(leaky(as_c.x + ad_c.x)), __expf(leaky(as_c.y + ad_c.y)),
                             __expf(leaky(as_c.z + ad_c.z)), __expf(leaky(as_c.w + ad_c.w)));
        }
        float4 sm = ex;
        #pragma unroll
        for (int m = 32; m >= 1; m >>= 1) {
            sm.x += __shfl_xor(sm.x, m, 64);
            sm.y += __shfl_xor(sm.y, m, 64);
            sm.z += __shfl_xor(sm.z, m, 64);
            sm.w += __shfl_xor(sm.w, m, 64);
        }
        salpha[wv][0][lane] = ex.x / (sm.x + 1e-16f);   // 0 beyond degT
        salpha[wv][1][lane] = ex.y / (sm.y + 1e-16f);
        salpha[wv][2][lane] = ex.z / (sm.z + 1e-16f);
        salpha[wv][3][lane] = ex.w / (sm.w + 1e-16f);
        // wave-private LDS: lgkmcnt ordering suffices, no barrier

        // ---- prefetch next node (overlaps the PV loop below) ----
        if (it < 7) {
            dl_n = wv * 8 + it + 1;
            d_n = bin * 64 + hsub * 32 + dl_n;
            deg_n = min(cnt2[dl_n], 63);
            myS_n = 0;
            as_n = make_float4(0.f, 0.f, 0.f, 0.f);
            if (lane < deg_n + 1) {
                myS_n = (lane < deg_n) ? (int)slotsrc[dl_n * 64 + lane] : d_n;
                as_n = as4[myS_n];
            }
            ad_n = ad4[d_n];
        }

        // ---- PV gather: 8 independent chains, 32 slots/iteration ----
        float2 a0 = {0.f, 0.f}, a1 = {0.f, 0.f}, a2 = {0.f, 0.f}, a3 = {0.f, 0.f};
#define ACC4(hv, al)                                                         \
        do {                                                                 \
            float2 f0 = __half22float2(__builtin_bit_cast(__half2, hv.x));   \
            float2 f1 = __half22float2(__builtin_bit_cast(__half2, hv.y));   \
            float2 f2 = __half22float2(__builtin_bit_cast(__half2, hv.z));   \
            float2 f3 = __half22float2(__builtin_bit_cast(__half2, hv.w));   \
            a0.x += f0.x * al; a0.y += f0.y * al;                            \
            a1.x += f1.x * al; a1.y += f1.y * al;                            \
            a2.x += f2.x * al; a2.y += f2.y * al;                            \
            a3.x += f3.x * al; a3.y += f3.y * al;                            \
        } while (0)

        for (int kk0 = 0; kk0 < degT_c; kk0 += 32) {  // wave-uniform
            int kb = kk0 + g;                          // <= 35 first pass
            int s0 = __shfl(myS_c, kb,      64);
            int s1 = __shfl(myS_c, kb + 4,  64);
            int s2 = __shfl(myS_c, kb + 8,  64);
            int s3 = __shfl(myS_c, kb + 12, 64);
            int s4 = __shfl(myS_c, kb + 16, 64);
            int s5 = __shfl(myS_c, kb + 20, 64);
            int s6 = __shfl(myS_c, kb + 24, 64);
            int s7 = __shfl(myS_c, kb + 28, 64);
            float l0 = ap[kb];                         // 0 for k >= degT
            float l1 = ap[kb + 4];
            float l2 = ap[kb + 8];
            float l3 = ap[kb + 12];
            float l4 = ap[kb + 16];
            float l5 = ap[kb + 20];
            float l6 = ap[kb + 24];
            float l7 = ap[kb + 28];
            float4 h0 = h4[(unsigned)(s0 * 16 + c4)];
            float4 h1 = h4[(unsigned)(s1 * 16 + c4)];
            float4 h2_ = h4[(unsigned)(s2 * 16 + c4)];
            float4 h3 = h4[(unsigned)(s3 * 16 + c4)];
            float4 h4_ = h4[(unsigned)(s4 * 16 + c4)];
            float4 h5 = h4[(unsigned)(s5 * 16 + c4)];
            float4 h6 = h4[(unsigned)(s6 * 16 + c4)];
            float4 h7 = h4[(unsigned)(s7 * 16 + c4)];
            ACC4(h0, l0);
            ACC4(h1, l1);
            ACC4(h2_, l2);
            ACC4(h3, l3);
            ACC4(h4_, l4);
            ACC4(h5, l5);
            ACC4(h6, l6);
            ACC4(h7, l7);
        }
#undef ACC4
        #pragma unroll
        for (int msk = 16; msk <= 32; msk <<= 1) {
            a0.x += __shfl_xor(a0.x, msk, 64); a0.y += __shfl_xor(a0.y, msk, 64);
            a1.x += __shfl_xor(a1.x, msk, 64); a1.y += __shfl_xor(a1.y, msk, 64);
            a2.x += __shfl_xor(a2.x, msk, 64); a2.y += __shfl_xor(a2.y, msk, 64);
            a3.x += __shfl_xor(a3.x, msk, 64); a3.y += __shfl_xor(a3.y, msk, 64);
        }
        if (d_c < n) {
            s8[0] += a0.x; q8[0] += a0.x * a0.x;
            s8[1] += a0.y; q8[1] += a0.y * a0.y;
            s8[2] += a1.x; q8[2] += a1.x * a1.x;
            s8[3] += a1.y; q8[3] += a1.y * a1.y;
            s8[4] += a2.x; q8[4] += a2.x * a2.x;
            s8[5] += a2.y; q8[5] += a2.y * a2.y;
            s8[6] += a3.x; q8[6] += a3.x * a3.x;
            s8[7] += a3.y; q8[7] += a3.y * a3.y;

            if (g == 0) {
                ((float4*)out)[(size_t)d_c * 32 + 2 * c4] =
                    make_float4(a0.x + b0.x, a0.y + b0.y, a1.x + b0.z, a1.y + b0.w);
            } else if (g == 1) {
                ((float4*)out)[(size_t)d_c * 32 + 2 * c4 + 1] =
                    make_float4(a2.x + b1.x, a2.y + b1.y, a3.x + b1.z, a3.y + b1.w);
            }
        }
    }

    // block reduction of BN partials -> pbuf[block][256] (128 sum | 128 sumsq)
    if (g == 0) {
        #pragma unroll
        for (int j = 0; j < 8; ++j) {
            pb[wv][8 * c4 + j]       = s8[j];
            pb[wv][128 + 8 * c4 + j] = q8[j];
        }
    }
    __syncthreads();
    {
        int t = threadIdx.x;
        float v = pb[0][t] + pb[1][t] + pb[2][t] + pb[3][t];
        pbuf[(size_t)(pboff + blockIdx.x) * 256 + t] = v;
    }
}

// ======== BN reduce: 128 blocks (one per channel) over pbuf partials ========
// sums/sumsq include the bias shift analytically: out = agg + b.
__global__ __launch_bounds__(256) void k_bn_reduce(
    const float* __restrict__ pbuf, const float* __restrict__ bias,
    float* __restrict__ sums, float* __restrict__ sumsq, int nb2, int n)
{
    __shared__ float ls[256], lq[256];
    const int c = blockIdx.x;
    const int t = threadIdx.x;
    float S = 0.f, Q = 0.f;
    for (int b = t; b < nb2; b += 256) {
        S += pbuf[(size_t)b * 256 + c];
        Q += pbuf[(size_t)b * 256 + 128 + c];
    }
    ls[t] = S; lq[t] = Q;
    __syncthreads();
    for (int off = 128; off >= 1; off >>= 1) {
        if (t < off) { ls[t] += ls[t + off]; lq[t] += lq[t + off]; }
        __syncthreads();
    }
    if (t == 0) {
        float b_ = bias[c];
        float Sr = ls[0], Qr = lq[0];
        sums[c]  = Sr + (float)n * b_;
        sumsq[c] = Qr + 2.f * b_ * Sr + (float)n * b_ * b_;
    }
}

// ======== BN apply + ReLU ========
__global__ __launch_bounds__(256) void k_bn_apply(
    float* __restrict__ out, const float* __restrict__ sums,
    const float* __restrict__ sumsq, const float* __restrict__ gamma,
    const float* __restrict__ beta, int n, int total)
{
    int i = blockIdx.x * 256 + threadIdx.x;
    if (i >= total) return;
    int c = i & 127;
    float invn = 1.0f / (float)n;
    float mean = sums[c] * invn;
    float var = sumsq[c] * invn - mean * mean;
    float v = out[i];
    float y = (v - mean) * rsqrtf(var + BN_EPS) * gamma[c] + beta[c];
    out[i] = fmaxf(y, 0.0f);
}

extern "C" void kernel_launch(void* const* d_in, const int* in_sizes, int n_in,
                              void* d_out, int out_size, void* d_ws, size_t ws_size,
                              hipStream_t stream)
{
    const float* x     = (const float*)d_in[0];
    const int*   ei    = (const int*)d_in[1];
    const float* w     = (const float*)d_in[2];
    const float* att_s = (const float*)d_in[3];
    const float* att_d = (const float*)d_in[4];
    const float* bias  = (const float*)d_in[5];
    const float* gamma = (const float*)d_in[6];
    const float* beta  = (const float*)d_in[7];

    const int n = in_sizes[0] / 128;
    const int E = in_sizes[1] / 2;
    const int total = n * 128;
    float* out = (float*)d_out;

    // ws layout (~28.9 MB, inside the proven envelope):
    // h2[n*64] half2 | a_src[n*4] f | a_dst[n*4] f | sums[128] f |
    // sumsq[128] f | binbuf[NB*4096] i | pbuf[2*NB*256] f | bincnt[NBMAX*16] i
    float*   ws    = (float*)d_ws;
    __half2* h2    = (__half2*)ws;
    float*   a_src = ws + (size_t)n * 64;
    float*   a_dst = a_src + (size_t)n * 4;
    float*   sums  = a_dst + (size_t)n * 4;
    float*   sumsq = sums + 128;
    int*     binbuf = (int*)(sumsq + 128);

    const int NB  = (n + 63) >> 6;              // bins of 64 nodes
    float*   pbuf  = (float*)(binbuf + (size_t)NB * 4096);
    int*     bincnt = (int*)(pbuf + (size_t)2 * NB * 256);

    const int* esrc = ei;
    const int* edst = ei + E;

    const int gb  = (n + 63) / 64;              // gemm blocks
    const int eb  = (E + EPB - 1) / EPB;        // edge blocks (1024 threads)
    const int NBH = NB / 2;                     // k_node half-split (attribution)
    const int nbA = 2 * NBH;
    const int nbB = 2 * (NB - NBH);
    const int nb2 = nbA + nbB;

    hipMemsetAsync(bincnt, 0, (size_t)NBMAX * 16 * sizeof(int), stream);
    k_edge<<<eb, 1024, 0, stream>>>(bincnt, binbuf, esrc, edst, E);
    k_gemm<<<gb, 256, 0, stream>>>(x, w, h2, att_s, att_d, a_src, a_dst, n);
    k_node<<<nbA, 256, 0, stream>>>(bincnt, binbuf, a_src, a_dst, h2, bias,
                                    out, pbuf, n, 0, 0);
    k_node<<<nbB, 256, 0, stream>>>(bincnt, binbuf, a_src, a_dst, h2, bias,
                                    out, pbuf, n, NBH, nbA);
    k_bn_reduce<<<128, 256, 0, stream>>>(pbuf, bias, sums, sumsq, nb2, n);
    k_bn_apply<<<(total + 255) / 256, 256, 0, stream>>>(out, sums, sumsq, gamma, beta, n, total);
}

// Round 9
// 178.413 us; speedup vs baseline: 1.1387x; 1.1387x over previous
//
#include <hip/hip_runtime.h>
#include <hip/hip_fp16.h>
#include <hip/hip_bf16.h>
#include <math.h>

#define NEG_SLOPE 0.2f
#define BN_EPS 1e-5f
#define EPB 4096          // edges per edge-role block (16 iters of 256)
#define NBMAX 1024        // max bins (64 nodes/bin) -> supports n <= 65536

typedef short  bf16x8 __attribute__((ext_vector_type(8)));
typedef float  f32x4  __attribute__((ext_vector_type(4)));

__device__ __forceinline__ float leaky(float v) {
    return v > 0.0f ? v : NEG_SLOPE * v;
}

__device__ __forceinline__ short bfbits(float f) {
    __hip_bfloat16 h = __float2bfloat16(f);
    return __builtin_bit_cast(short, h);
}

__device__ __forceinline__ bf16x8 cvt8(const float* p) {
    float4 u = *(const float4*)p;
    float4 v = *(const float4*)(p + 4);
    bf16x8 a;
    a[0] = bfbits(u.x); a[1] = bfbits(u.y); a[2] = bfbits(u.z); a[3] = bfbits(u.w);
    a[4] = bfbits(v.x); a[5] = bfbits(v.y); a[6] = bfbits(v.z); a[7] = bfbits(v.w);
    return a;
}

// LDS union: gemm role uses wl (32KB bf16 weights); edge role uses e.*
// (hist 4KB + gbase 4KB + sorted 16KB = 24KB). 32KB total -> 4 blocks/CU.
union SharedU {
    short wl[16384];
    struct { int hist[NBMAX]; int gbase[NBMAX]; int sorted[EPB]; } e;
};

// ======== k_fused: edge counting-sort + MFMA GEMM as block roles ============
// R8 discovery: the 43us/256MiB workspace re-poison fills cap top-5 -- all
// our kernels are <43us and invisible; dur_us ~= 43 (poison) + kernels.
// k_edge and k_gemm are INDEPENDENT but sequential dispatches serialize.
// R1's fused=sum failure paired gemm with the scatter-heavy edge path (both
// VMEM-queue-bound). The counting-sort edge path is LDS/atomic-heavy with
// light VMEM -- complementary to gemm's VMEM+MFMA+ds_read -- so co-resident
// role blocks (4 gemm : 1 edge, 4 blocks/CU) should overlap: fused ~= max,
// not sum. If this lands at ~sum again, block-role overlap is dead for good.
__global__ __launch_bounds__(256) void k_fused(
    const float* __restrict__ x, const float* __restrict__ w,
    __half2* __restrict__ h2, const float* __restrict__ att_s,
    const float* __restrict__ att_d, float* __restrict__ a_src,
    float* __restrict__ a_dst, int* __restrict__ bincnt,
    int* __restrict__ binbuf, const int* __restrict__ esrc,
    const int* __restrict__ edst, int n, int E, int gb, int eb)
{
    __shared__ SharedU sh;
    const int tid = threadIdx.x;
    const int q = blockIdx.x / 5;
    const int r = blockIdx.x % 5;

    if (r == 4) {
        // ---- edge role: per-block LDS counting sort, coalesced binned out ---
        const int blk = q;
        if (blk >= eb) return;
        const int e0 = blk * EPB;
        const int ecnt = min(EPB, E - e0);
        int* hist = sh.e.hist;
        int* gbase = sh.e.gbase;
        int* sorted = sh.e.sorted;
        __shared__ int wsum[4];

        for (int i = tid; i < NBMAX; i += 256) hist[i] = 0;
        __syncthreads();

        for (int i = tid; i < ecnt; i += 256)
            atomicAdd(&hist[(unsigned)edst[e0 + i] >> 6], 1);
        __syncthreads();

        // exclusive prefix over NBMAX bins; thread t owns bins 4t..4t+3
        int4 hh = ((int4*)hist)[tid];
        int tot = hh.x + hh.y + hh.z + hh.w;
        int sc = tot;
        const int lane = tid & 63;
        const int wv = tid >> 6;
        #pragma unroll
        for (int off = 1; off < 64; off <<= 1) {
            int v = __shfl_up(sc, off, 64);
            if (lane >= off) sc += v;
        }
        if (lane == 63) wsum[wv] = sc;
        __syncthreads();
        int base = sc - tot;                    // wave-exclusive
        #pragma unroll
        for (int w_ = 0; w_ < 4; ++w_) if (w_ < wv) base += wsum[w_];

        int l0 = base, l1 = l0 + hh.x, l2 = l1 + hh.y, l3 = l2 + hh.z;
        if (hh.x > 0) gbase[4 * tid + 0] =
            ((4 * tid + 0) << 12) + atomicAdd(&bincnt[(4 * tid + 0) * 16], hh.x) - l0;
        if (hh.y > 0) gbase[4 * tid + 1] =
            ((4 * tid + 1) << 12) + atomicAdd(&bincnt[(4 * tid + 1) * 16], hh.y) - l1;
        if (hh.z > 0) gbase[4 * tid + 2] =
            ((4 * tid + 2) << 12) + atomicAdd(&bincnt[(4 * tid + 2) * 16], hh.z) - l2;
        if (hh.w > 0) gbase[4 * tid + 3] =
            ((4 * tid + 3) << 12) + atomicAdd(&bincnt[(4 * tid + 3) * 16], hh.w) - l3;
        __syncthreads();
        hist[4 * tid + 0] = l0;                 // cursor init = local base
        hist[4 * tid + 1] = l1;
        hist[4 * tid + 2] = l2;
        hist[4 * tid + 3] = l3;
        __syncthreads();

        // scatter into LDS-sorted order (LDS atomics: per-CU, cheap)
        for (int i = tid; i < ecnt; i += 256) {
            int s = esrc[e0 + i];
            int d = edst[e0 + i];
            int pos = atomicAdd(&hist[(unsigned)d >> 6], 1);
            sorted[pos] = s | (d << 16);
        }
        __syncthreads();

        // write out: runs contiguous in LDS and global -> coalesced
        for (int i = tid; i < ecnt; i += 256) {
            int rec = sorted[i];
            unsigned bin = (unsigned)rec >> 22;
            int dest = gbase[bin] + i;
            if (dest < (int)((bin + 1) << 12))  // overflow guard (never fires)
                binbuf[dest] = rec;
        }
        return;
    }

    // ---- gemm role: one wave = 16 rows x 128 cols, w staged bf16 in LDS ----
    const int bb = q * 4 + r;
    if (bb >= gb) return;
    short* wl = sh.wl;

    for (int f = tid; f < 2048; f += 256) {
        int m_   = f & 15;
        int g_   = (f >> 4) & 7;
        int q_   = (f >> 7) & 3;
        int k0_  = f >> 9;
        bf16x8 v = cvt8(&w[(size_t)(16 * g_ + m_) * 128 + k0_ * 32 + q_ * 8]);
        *(bf16x8*)&wl[f * 8] = v;
    }
    __syncthreads();

    const int wave = tid >> 6;
    const int lane = tid & 63;
    const int m = lane & 15;
    const int quad = lane >> 4;
    const int r0w = bb * 64 + wave * 16;

    f32x4 acc[8];
    #pragma unroll
    for (int g = 0; g < 8; ++g) acc[g] = (f32x4){0.f, 0.f, 0.f, 0.f};

    const int arow = min(r0w + m, n - 1);
    const float* xrow = x + (size_t)arow * 128 + quad * 8;

    #pragma unroll
    for (int k0 = 0; k0 < 4; ++k0) {
        bf16x8 a = cvt8(xrow + k0 * 32);
        #pragma unroll
        for (int g = 0; g < 8; ++g) {
            bf16x8 b = *(const bf16x8*)&wl[(((k0 * 4 + quad) * 8 + g) * 16 + m) * 8];
            acc[g] = __builtin_amdgcn_mfma_f32_16x16x32_bf16(a, b, acc[g], 0, 0, 0);
        }
    }

    float asv[8], adv[8];
    #pragma unroll
    for (int g = 0; g < 8; ++g) {
        asv[g] = att_s[16 * g + m];
        adv[g] = att_d[16 * g + m];
    }
    float ss[4][4], sd[4][4];          // [reg][head]
    #pragma unroll
    for (int reg = 0; reg < 4; ++reg) {
        #pragma unroll
        for (int h = 0; h < 4; ++h) {
            float ps = acc[2 * h][reg] * asv[2 * h] + acc[2 * h + 1][reg] * asv[2 * h + 1];
            float pd = acc[2 * h][reg] * adv[2 * h] + acc[2 * h + 1][reg] * adv[2 * h + 1];
            #pragma unroll
            for (int msk = 1; msk <= 8; msk <<= 1) {
                ps += __shfl_xor(ps, msk, 64);
                pd += __shfl_xor(pd, msk, 64);
            }
            ss[reg][h] = ps; sd[reg][h] = pd;
        }
    }
    if (m == 0) {
        #pragma unroll
        for (int reg = 0; reg < 4; ++reg) {
            int grow = r0w + quad * 4 + reg;
            if (grow < n) {
                ((float4*)a_src)[grow] = make_float4(ss[reg][0], ss[reg][1], ss[reg][2], ss[reg][3]);
                ((float4*)a_dst)[grow] = make_float4(sd[reg][0], sd[reg][1], sd[reg][2], sd[reg][3]);
            }
        }
    }

    #pragma unroll
    for (int reg = 0; reg < 4; ++reg) {
        int grow = r0w + quad * 4 + reg;
        #pragma unroll
        for (int g = 0; g < 8; ++g) {
            float v0 = acc[g][reg];
            float v1 = __shfl_xor(v0, 1, 64);
            if (!(m & 1) && grow < n)
                h2[(size_t)grow * 64 + 8 * g + (m >> 1)] = __floats2half2_rn(v0, v1);
        }
    }
}

// ======== k_node: R7-proven version (52us) -- sub-bin in-LDS ELL + agg ======
// R8 lesson: deep-MLP (32-slot gather) + half-split REGRESSED ~+11us --
// the wider gather doubles padded slot-fetches for the ~46% of nodes with
// degT<=16. Reverted verbatim to the R7 structure: 2 blocks/bin, 4 chains,
// 16 slots/iter. salpha stride 72: gather bank = 8*head+g -> 16 banks.
// Lanes >= degT keep myS=0 -> padded gathers hit node 0's row (L1-hot),
// alpha exactly 0. All shfl sites run with all 64 lanes active.
__global__ __launch_bounds__(256) void k_node(
    const int* __restrict__ bincnt, const int* __restrict__ binbuf,
    const float* __restrict__ a_src, const float* __restrict__ a_dst,
    const __half2* __restrict__ h2, const float* __restrict__ bias,
    float* __restrict__ out, float* __restrict__ pbuf, int n)
{
    __shared__ unsigned short slotsrc[32 * 64];
    __shared__ int cnt2[32];
    __shared__ float salpha[4][4][72];
    __shared__ float pb[4][256];
    const int bin = blockIdx.x >> 1;
    const int hsub = blockIdx.x & 1;
    const int tid = threadIdx.x;

    if (tid < 32) cnt2[tid] = 0;
    __syncthreads();

    const int cnt = min(bincnt[bin * 16], 4096);
    const int* bb = binbuf + (size_t)bin * 4096;
    for (int i = tid; i < cnt; i += 256) {
        int e = bb[i];
        int d6 = (e >> 16) & 63;
        if ((d6 >> 5) == hsub) {
            int o = atomicAdd(&cnt2[d6 & 31], 1);
            if (o < 63) slotsrc[(d6 & 31) * 64 + o] = (unsigned short)e;
        }
    }
    __syncthreads();

    const int wv = tid >> 6;
    const int lane = tid & 63;
    const int g  = lane >> 4;
    const int c4 = lane & 15;
    const int head = c4 >> 2;
    const float* ap = &salpha[wv][head][0];
    const float4* h4 = (const float4*)h2;
    const float4 b0 = ((const float4*)bias)[2 * c4];
    const float4 b1 = ((const float4*)bias)[2 * c4 + 1];

    float s8[8], q8[8];
    #pragma unroll
    for (int j = 0; j < 8; ++j) { s8[j] = 0.f; q8[j] = 0.f; }

    for (int it = 0; it < 8; ++it) {
        const int dl = wv * 8 + it;           // wave-uniform local node
        const int d = bin * 64 + hsub * 32 + dl;
        if (d >= n) break;                    // wave-uniform exit
        const int deg = min(cnt2[dl], 63);
        const int degT = deg + 1;             // + synthesized self-loop
        const float4 ad = ((const float4*)a_dst)[d];

        int myS = 0;
        float4 ex = make_float4(0.f, 0.f, 0.f, 0.f);
        if (lane < degT) {
            myS = (lane < deg) ? (int)slotsrc[dl * 64 + lane] : d;
            float4 as = ((const float4*)a_src)[myS];
            ex = make_float4(__expf(leaky(as.x + ad.x)), __expf(leaky(as.y + ad.y)),
                             __expf(leaky(as.z + ad.z)), __expf(leaky(as.w + ad.w)));
        }
        float4 sm = ex;
        #pragma unroll
        for (int m = 32; m >= 1; m >>= 1) {
            sm.x += __shfl_xor(sm.x, m, 64);
            sm.y += __shfl_xor(sm.y, m, 64);
            sm.z += __shfl_xor(sm.z, m, 64);
            sm.w += __shfl_xor(sm.w, m, 64);
        }
        salpha[wv][0][lane] = ex.x / (sm.x + 1e-16f);   // 0 beyond degT
        salpha[wv][1][lane] = ex.y / (sm.y + 1e-16f);
        salpha[wv][2][lane] = ex.z / (sm.z + 1e-16f);
        salpha[wv][3][lane] = ex.w / (sm.w + 1e-16f);
        // wave-private LDS: lgkmcnt ordering suffices, no barrier

        float2 a0 = {0.f, 0.f}, a1 = {0.f, 0.f}, a2 = {0.f, 0.f}, a3 = {0.f, 0.f};
#define ACC4(hv, al)                                                         \
        do {                                                                 \
            float2 f0 = __half22float2(__builtin_bit_cast(__half2, hv.x));   \
            float2 f1 = __half22float2(__builtin_bit_cast(__half2, hv.y));   \
            float2 f2 = __half22float2(__builtin_bit_cast(__half2, hv.z));   \
            float2 f3 = __half22float2(__builtin_bit_cast(__half2, hv.w));   \
            a0.x += f0.x * al; a0.y += f0.y * al;                            \
            a1.x += f1.x * al; a1.y += f1.y * al;                            \
            a2.x += f2.x * al; a2.y += f2.y * al;                            \
            a3.x += f3.x * al; a3.y += f3.y * al;                            \
        } while (0)

        for (int kk0 = 0; kk0 < degT; kk0 += 16) {  // wave-uniform; kk0 <= 48
            int kA = kk0 + g;
            int kB = kk0 + 4 + g;
            int kC = kk0 + 8 + g;
            int kD = kk0 + 12 + g;
            int sA = __shfl(myS, kA, 64);
            int sB = __shfl(myS, kB, 64);
            int sC = __shfl(myS, kC, 64);
            int sD = __shfl(myS, kD, 64);
            float alA = ap[kA];                     // 0 for k >= degT
            float alB = ap[kB];
            float alC = ap[kC];
            float alD = ap[kD];
            float4 hA = h4[(unsigned)(sA * 16 + c4)];
            float4 hB = h4[(unsigned)(sB * 16 + c4)];
            float4 hC = h4[(unsigned)(sC * 16 + c4)];
            float4 hD = h4[(unsigned)(sD * 16 + c4)];
            ACC4(hA, alA);
            ACC4(hB, alB);
            ACC4(hC, alC);
            ACC4(hD, alD);
        }
#undef ACC4
        #pragma unroll
        for (int msk = 16; msk <= 32; msk <<= 1) {
            a0.x += __shfl_xor(a0.x, msk, 64); a0.y += __shfl_xor(a0.y, msk, 64);
            a1.x += __shfl_xor(a1.x, msk, 64); a1.y += __shfl_xor(a1.y, msk, 64);
            a2.x += __shfl_xor(a2.x, msk, 64); a2.y += __shfl_xor(a2.y, msk, 64);
            a3.x += __shfl_xor(a3.x, msk, 64); a3.y += __shfl_xor(a3.y, msk, 64);
        }
        s8[0] += a0.x; q8[0] += a0.x * a0.x;
        s8[1] += a0.y; q8[1] += a0.y * a0.y;
        s8[2] += a1.x; q8[2] += a1.x * a1.x;
        s8[3] += a1.y; q8[3] += a1.y * a1.y;
        s8[4] += a2.x; q8[4] += a2.x * a2.x;
        s8[5] += a2.y; q8[5] += a2.y * a2.y;
        s8[6] += a3.x; q8[6] += a3.x * a3.x;
        s8[7] += a3.y; q8[7] += a3.y * a3.y;

        if (g == 0) {
            ((float4*)out)[(size_t)d * 32 + 2 * c4] =
                make_float4(a0.x + b0.x, a0.y + b0.y, a1.x + b0.z, a1.y + b0.w);
        } else if (g == 1) {
            ((float4*)out)[(size_t)d * 32 + 2 * c4 + 1] =
                make_float4(a2.x + b1.x, a2.y + b1.y, a3.x + b1.z, a3.y + b1.w);
        }
    }

    // block reduction of BN partials -> pbuf[block][256] (128 sum | 128 sumsq)
    if (g == 0) {
        #pragma unroll
        for (int j = 0; j < 8; ++j) {
            pb[wv][8 * c4 + j]       = s8[j];
            pb[wv][128 + 8 * c4 + j] = q8[j];
        }
    }
    __syncthreads();
    {
        int t = threadIdx.x;
        float v = pb[0][t] + pb[1][t] + pb[2][t] + pb[3][t];
        pbuf[(size_t)blockIdx.x * 256 + t] = v;
    }
}

// ======== BN reduce: 128 blocks (one per channel) over pbuf partials ========
// sums/sumsq include the bias shift analytically: out = agg + b.
__global__ __launch_bounds__(256) void k_bn_reduce(
    const float* __restrict__ pbuf, const float* __restrict__ bias,
    float* __restrict__ sums, float* __restrict__ sumsq, int nb2, int n)
{
    __shared__ float ls[256], lq[256];
    const int c = blockIdx.x;
    const int t = threadIdx.x;
    float S = 0.f, Q = 0.f;
    for (int b = t; b < nb2; b += 256) {
        S += pbuf[(size_t)b * 256 + c];
        Q += pbuf[(size_t)b * 256 + 128 + c];
    }
    ls[t] = S; lq[t] = Q;
    __syncthreads();
    for (int off = 128; off >= 1; off >>= 1) {
        if (t < off) { ls[t] += ls[t + off]; lq[t] += lq[t + off]; }
        __syncthreads();
    }
    if (t == 0) {
        float b_ = bias[c];
        float Sr = ls[0], Qr = lq[0];
        sums[c]  = Sr + (float)n * b_;
        sumsq[c] = Qr + 2.f * b_ * Sr + (float)n * b_ * b_;
    }
}

// ======== BN apply + ReLU: float4-vectorized (4 consecutive channels) =======
__global__ __launch_bounds__(256) void k_bn_apply(
    float* __restrict__ out, const float* __restrict__ sums,
    const float* __restrict__ sumsq, const float* __restrict__ gamma,
    const float* __restrict__ beta, int n, int total4)
{
    int i = blockIdx.x * 256 + threadIdx.x;
    if (i >= total4) return;
    int c = (i * 4) & 127;                 // c % 4 == 0
    float invn = 1.0f / (float)n;
    float4 S = *(const float4*)&sums[c];
    float4 Q = *(const float4*)&sumsq[c];
    float4 G = *(const float4*)&gamma[c];
    float4 B = *(const float4*)&beta[c];
    float4 v = ((float4*)out)[i];
    float m0 = S.x * invn, m1 = S.y * invn, m2 = S.z * invn, m3 = S.w * invn;
    float4 y;
    y.x = fmaxf((v.x - m0) * rsqrtf(Q.x * invn - m0 * m0 + BN_EPS) * G.x + B.x, 0.f);
    y.y = fmaxf((v.y - m1) * rsqrtf(Q.y * invn - m1 * m1 + BN_EPS) * G.y + B.y, 0.f);
    y.z = fmaxf((v.z - m2) * rsqrtf(Q.z * invn - m2 * m2 + BN_EPS) * G.z + B.z, 0.f);
    y.w = fmaxf((v.w - m3) * rsqrtf(Q.w * invn - m3 * m3 + BN_EPS) * G.w + B.w, 0.f);
    ((float4*)out)[i] = y;
}

extern "C" void kernel_launch(void* const* d_in, const int* in_sizes, int n_in,
                              void* d_out, int out_size, void* d_ws, size_t ws_size,
                              hipStream_t stream)
{
    const float* x     = (const float*)d_in[0];
    const int*   ei    = (const int*)d_in[1];
    const float* w     = (const float*)d_in[2];
    const float* att_s = (const float*)d_in[3];
    const float* att_d = (const float*)d_in[4];
    const float* bias  = (const float*)d_in[5];
    const float* gamma = (const float*)d_in[6];
    const float* beta  = (const float*)d_in[7];

    const int n = in_sizes[0] / 128;
    const int E = in_sizes[1] / 2;
    const int total = n * 128;
    float* out = (float*)d_out;

    // ws layout (~28.9 MB):
    // h2[n*64] half2 | a_src[n*4] f | a_dst[n*4] f | sums[128] f |
    // sumsq[128] f | binbuf[NB*4096] i | pbuf[2*NB*256] f | bincnt[NBMAX*16] i
    float*   ws    = (float*)d_ws;
    __half2* h2    = (__half2*)ws;
    float*   a_src = ws + (size_t)n * 64;
    float*   a_dst = a_src + (size_t)n * 4;
    float*   sums  = a_dst + (size_t)n * 4;
    float*   sumsq = sums + 128;
    int*     binbuf = (int*)(sumsq + 128);

    const int NB  = (n + 63) >> 6;              // bins of 64 nodes
    float*   pbuf  = (float*)(binbuf + (size_t)NB * 4096);
    int*     bincnt = (int*)(pbuf + (size_t)2 * NB * 256);

    const int* esrc = ei;
    const int* edst = ei + E;

    const int gb = (n + 63) / 64;               // gemm role blocks (782)
    const int eb = (E + EPB - 1) / EPB;         // edge role blocks (196)
    // interleave 4 gemm : 1 edge; grid covers both roles with guards
    const int periods = max((gb + 3) / 4, eb);
    const int fused_blocks = periods * 5;
    const int nb2 = 2 * NB;                     // k_node blocks (sub-bins)

    hipMemsetAsync(bincnt, 0, (size_t)NBMAX * 16 * sizeof(int), stream);
    k_fused<<<fused_blocks, 256, 0, stream>>>(x, w, h2, att_s, att_d,
                                              a_src, a_dst, bincnt, binbuf,
                                              esrc, edst, n, E, gb, eb);
    k_node<<<nb2, 256, 0, stream>>>(bincnt, binbuf, a_src, a_dst, h2, bias, out, pbuf, n);
    k_bn_reduce<<<128, 256, 0, stream>>>(pbuf, bias, sums, sumsq, nb2, n);
    k_bn_apply<<<(total / 4 + 255) / 256, 256, 0, stream>>>(out, sums, sumsq,
                                                            gamma, beta, n, total / 4);
}